// Round 8
// baseline (351.852 us; speedup 1.0000x reference)
//
#include <hip/hip_runtime.h>
#include <hip/hip_bf16.h>
#include <math.h>

// Problem constants
#define B_   32
#define SX_  512
#define SM_  4096
#define D_   256
#define TOPK_ 5

// GEMM tiling
#define BM 128
#define BN 128
#define BK 32

typedef _Float16 half8 __attribute__((ext_vector_type(8)));
typedef _Float16 half4 __attribute__((ext_vector_type(4)));
typedef float    f32x4  __attribute__((ext_vector_type(4)));
typedef float    f32x16 __attribute__((ext_vector_type(16)));

#define GLOBAL_AS const __attribute__((address_space(1))) void*
#define LDS_AS    __attribute__((address_space(3))) void*

// ---------------------------------------------------------------------------
// Kernel 1 (big-ws path): fused inv-norm + split-fp16 prep.
// Writes hi/lo fp16 of (row * invnorm(row) * 16). Uniform scaling preserves
// top-k order exactly. One wave per row.
// ---------------------------------------------------------------------------
__global__ __launch_bounds__(256) void prep_kernel(
    const float* __restrict__ in,
    _Float16* __restrict__ hi_out, _Float16* __restrict__ lo_out, int nrows)
{
    const int row  = blockIdx.x * 4 + (threadIdx.x >> 6);
    const int lane = threadIdx.x & 63;
    if (row >= nrows) return;
    const float4 v = *(const float4*)(in + (size_t)row * D_ + lane * 4);
    float s = v.x * v.x + v.y * v.y + v.z * v.z + v.w * v.w;
    #pragma unroll
    for (int off = 32; off > 0; off >>= 1) s += __shfl_xor(s, off);
    const float scale = 16.0f / sqrtf(s);
    const float f[4] = {v.x * scale, v.y * scale, v.z * scale, v.w * scale};
    half4 h, l;
    #pragma unroll
    for (int i = 0; i < 4; ++i) {
        h[i] = (_Float16)f[i];
        l[i] = (_Float16)(f[i] - (float)h[i]);
    }
    *(half4*)(hi_out + (size_t)row * D_ + lane * 4) = h;
    *(half4*)(lo_out + (size_t)row * D_ + lane * 4) = l;
}

// ---------------------------------------------------------------------------
// Kernel 2 (big-ws path): split-fp16 MFMA GEMM + row-max.
// R8: 32x32x16 MFMA (higher ceiling, half the instrs) + 512-thread blocks
// (8 waves, 2m x 4s, wave tile 64x32) for 2x occupancy at the same 65 KB LDS.
// Static double buffer + counted vmcnt(4) (R7-proven structure: stage ->
// vmcnt -> barrier -> ds_read+MFMA -> barrier; next-chunk loads stay in
// flight across barriers).
// A/B frag (32x32x16): lane l holds row l&31, k=(l>>5)*8+e.
// C/D (m74/m101-verified): col=lane&31, row=(reg&3)+8*(reg>>2)+4*(lane>>5).
// ---------------------------------------------------------------------------

// stage one [128][BK] k-chunk of all 4 operand arrays (4 loads/wave, 8 waves)
#define STAGE(DST, BH, BL, NK0) do {                                          \
    const int r_ = wid * 16 + lr;                                             \
    const int g_ = gp ^ ((r_ >> 1) & 3);                                      \
    const size_t so_ = (size_t)r_ * D_ + (NK0) + g_ * 8;                      \
    const int dof_ = (wid * 16) * BK;                                         \
    __builtin_amdgcn_global_load_lds((GLOBAL_AS)(Ah + so_), (LDS_AS)&DST[0][dof_], 16, 0, 0); \
    __builtin_amdgcn_global_load_lds((GLOBAL_AS)(Al + so_), (LDS_AS)&DST[1][dof_], 16, 0, 0); \
    __builtin_amdgcn_global_load_lds((GLOBAL_AS)((BH) + so_), (LDS_AS)&DST[2][dof_], 16, 0, 0); \
    __builtin_amdgcn_global_load_lds((GLOBAL_AS)((BL) + so_), (LDS_AS)&DST[3][dof_], 16, 0, 0); \
} while (0)

#define KSTEP(CUR, NXT, IT) do {                                              \
    if ((IT) + 1 < 32) {                                                      \
        const int nst_ = ((IT) + 1) >> 3;                                     \
        const int nk0_ = (((IT) + 1) & 7) * BK;                               \
        STAGE(NXT, Bh0 + (size_t)nst_ * BN * D_, Bl0 + (size_t)nst_ * BN * D_, nk0_); \
        asm volatile("s_waitcnt vmcnt(4)" ::: "memory");                      \
    } else {                                                                  \
        asm volatile("s_waitcnt vmcnt(0)" ::: "memory");                      \
    }                                                                         \
    __builtin_amdgcn_sched_barrier(0);                                        \
    __builtin_amdgcn_s_barrier();                                             \
    __builtin_amdgcn_sched_barrier(0);                                        \
    __builtin_amdgcn_s_setprio(1);                                            \
    _Pragma("unroll")                                                         \
    for (int ks_ = 0; ks_ < 2; ++ks_) {                                       \
        half8 ah_[2], al_[2];                                                 \
        _Pragma("unroll")                                                     \
        for (int mt_ = 0; mt_ < 2; ++mt_) {                                   \
            ah_[mt_] = *(const half8*)&CUR[0][aoff[mt_][ks_]];                \
            al_[mt_] = *(const half8*)&CUR[1][aoff[mt_][ks_]];                \
        }                                                                     \
        const half8 bh_ = *(const half8*)&CUR[2][boff[ks_]];                  \
        const half8 bl_ = *(const half8*)&CUR[3][boff[ks_]];                  \
        _Pragma("unroll")                                                     \
        for (int mt_ = 0; mt_ < 2; ++mt_)                                     \
            acc[mt_] = __builtin_amdgcn_mfma_f32_32x32x16_f16(ah_[mt_], bh_, acc[mt_], 0, 0, 0); \
        _Pragma("unroll")                                                     \
        for (int mt_ = 0; mt_ < 2; ++mt_)                                     \
            acc[mt_] = __builtin_amdgcn_mfma_f32_32x32x16_f16(ah_[mt_], bl_, acc[mt_], 0, 0, 0); \
        _Pragma("unroll")                                                     \
        for (int mt_ = 0; mt_ < 2; ++mt_)                                     \
            acc[mt_] = __builtin_amdgcn_mfma_f32_32x32x16_f16(al_[mt_], bh_, acc[mt_], 0, 0, 0); \
    }                                                                         \
    __builtin_amdgcn_s_setprio(0);                                            \
    __builtin_amdgcn_s_barrier();                                             \
    __builtin_amdgcn_sched_barrier(0);                                        \
} while (0)

__global__ __launch_bounds__(512) void gemm16_max_kernel(
    const _Float16* __restrict__ xh, const _Float16* __restrict__ xl,
    const _Float16* __restrict__ mh, const _Float16* __restrict__ ml,
    float* __restrict__ rowmax)
{
    __shared__ _Float16 ldsA[4][BM * BK];   // even k-chunks (32 KB)
    __shared__ _Float16 ldsB[4][BM * BK];   // odd  k-chunks (32 KB)
    __shared__ float red[4][BM];            // per-s-wave-group partial max

    // bijective XCD swizzle (1024 blocks % 8 == 0)
    const int lin = blockIdx.y * 32 + blockIdx.x;
    const int swz = (lin & 7) * 128 + (lin >> 3);
    const int b   = swz >> 5;
    const int m0  = (swz & 31) * BM;

    const int tid  = threadIdx.x;
    const int wid  = tid >> 6, lane = tid & 63;
    const int wm   = (wid >> 2) * 64;   // wave m-origin (2 m-groups)
    const int wsj  = (wid & 3) * 32;    // wave s-origin (4 s-groups)
    const int l31  = lane & 31;
    const int lhi  = lane >> 5;         // k-half selector
    const int lr   = lane >> 2;         // staging row within 16-row group
    const int gp   = lane & 3;          // staging dest granule

    const _Float16* Ah  = mh + ((size_t)b * SM_ + m0) * D_;
    const _Float16* Al  = ml + ((size_t)b * SM_ + m0) * D_;
    const _Float16* Bh0 = xh + (size_t)b * SX_ * D_;
    const _Float16* Bl0 = xl + (size_t)b * SX_ * D_;

    // fragment read offsets (fp16 elems): row r, k-granule (ks*2+lhi) ^ swz(r)
    int aoff[2][2], boff[2];
    #pragma unroll
    for (int mt = 0; mt < 2; ++mt) {
        const int ra = wm + mt * 32 + l31;
        #pragma unroll
        for (int ks = 0; ks < 2; ++ks)
            aoff[mt][ks] = ra * BK + (((ks * 2 + lhi) ^ ((ra >> 1) & 3)) << 3);
    }
    {
        const int rb = wsj + l31;
        #pragma unroll
        for (int ks = 0; ks < 2; ++ks)
            boff[ks] = rb * BK + (((ks * 2 + lhi) ^ ((rb >> 1) & 3)) << 3);
    }

    float part[2][16];
    #pragma unroll
    for (int mt = 0; mt < 2; ++mt)
        #pragma unroll
        for (int j = 0; j < 16; ++j) part[mt][j] = -INFINITY;

    STAGE(ldsA, Bh0, Bl0, 0);   // chunk 0 in flight (4 loads/wave)

    #pragma unroll 1
    for (int sti = 0; sti < 4; ++sti) {
        f32x16 acc[2];
        #pragma unroll
        for (int mt = 0; mt < 2; ++mt)
            #pragma unroll
            for (int j = 0; j < 16; ++j) acc[mt][j] = 0.0f;

        #pragma unroll 1
        for (int kp = 0; kp < 4; ++kp) {
            const int it = sti * 8 + kp * 2;
            KSTEP(ldsA, ldsB, it);
            KSTEP(ldsB, ldsA, it + 1);
        }
        // fold this s-tile into running row-max (register-only)
        #pragma unroll
        for (int mt = 0; mt < 2; ++mt)
            #pragma unroll
            for (int j = 0; j < 16; ++j)
                part[mt][j] = fmaxf(part[mt][j], acc[mt][j]);
    }

    // reduce across the 32 s-columns (lanes within the 32-group)
    #pragma unroll
    for (int off = 1; off < 32; off <<= 1)
        #pragma unroll
        for (int mt = 0; mt < 2; ++mt)
            #pragma unroll
            for (int j = 0; j < 16; ++j)
                part[mt][j] = fmaxf(part[mt][j], __shfl_xor(part[mt][j], off));

    if (l31 == 0) {   // lanes 0 and 32: rows +0 / +4 per C-layout
        #pragma unroll
        for (int mt = 0; mt < 2; ++mt)
            #pragma unroll
            for (int j = 0; j < 16; ++j)
                red[wid & 3][wm + mt * 32 + (j & 3) + 8 * (j >> 2) + 4 * lhi] = part[mt][j];
    }
    __syncthreads();
    if (tid < BM) {
        const float v = fmaxf(fmaxf(red[0][tid], red[1][tid]),
                              fmaxf(red[2][tid], red[3][tid]));
        rowmax[(size_t)b * SM_ + m0 + tid] = v;
    }
}

// ---------------------------------------------------------------------------
// Fallback path (small ws): R4 kernels, verified absmax 0 @ 168 us gemm.
// ---------------------------------------------------------------------------
__global__ __launch_bounds__(256) void invnorm_kernel(
    const float* __restrict__ in, float* __restrict__ out, int nrows)
{
    int row  = blockIdx.x * 4 + (threadIdx.x >> 6);
    int lane = threadIdx.x & 63;
    if (row >= nrows) return;
    const float4 v = *(const float4*)(in + (size_t)row * D_ + lane * 4);
    float s = v.x * v.x + v.y * v.y + v.z * v.z + v.w * v.w;
    #pragma unroll
    for (int off = 32; off > 0; off >>= 1) s += __shfl_xor(s, off);
    if (lane == 0) out[row] = 1.0f / sqrtf(s);
}

__device__ __forceinline__ int lds_off(int row, int k) {
    return row * 32 + ((((k >> 3) ^ ((row >> 1) & 3)) << 3) | (k & 7));
}

__global__ __launch_bounds__(256) void gemm_max_kernel(
    const float* __restrict__ x, const float* __restrict__ mem,
    const float* __restrict__ invnx, const float* __restrict__ invnm,
    float* __restrict__ rowmax)
{
    __shared__ union __align__(16) {
        _Float16 t[4][BM * BK];
        float red[2][BM];
    } u;

    const int b   = blockIdx.y;
    const int m0  = blockIdx.x * BM;
    const int tid = threadIdx.x;
    const int wid = tid >> 6, lane = tid & 63;
    const int wm  = (wid >> 1) * 64;
    const int wsj = (wid & 1) * 64;
    const float* memb = mem + ((size_t)b * SM_ + m0) * D_;
    const float* xb   = x   + (size_t)b * SX_ * D_;
    const int sr = tid >> 3;
    const int sc = (tid & 7) * 4;
    const int fm  = lane & 15;
    const int fkc = lane >> 4;

    float part[4][4];
    #pragma unroll
    for (int i = 0; i < 4; ++i)
        #pragma unroll
        for (int j = 0; j < 4; ++j) part[i][j] = -INFINITY;

    #pragma unroll 1
    for (int s0 = 0; s0 < SX_; s0 += BN) {
        f32x4 acc[4][4];
        #pragma unroll
        for (int i = 0; i < 4; ++i)
            #pragma unroll
            for (int j = 0; j < 4; ++j) acc[i][j] = (f32x4){0.f, 0.f, 0.f, 0.f};

        float4 ra[4], rb[4];
        #pragma unroll
        for (int p = 0; p < 4; ++p) {
            const int r = sr + 32 * p;
            ra[p] = *(const float4*)(memb + (size_t)r * D_ + sc);
            rb[p] = *(const float4*)(xb + (size_t)(s0 + r) * D_ + sc);
        }

        #pragma unroll 1
        for (int k0 = 0; k0 < D_; k0 += BK) {
            __syncthreads();
            #pragma unroll
            for (int p = 0; p < 4; ++p) {
                const int r  = sr + 32 * p;
                const int oa = lds_off(r, sc);
                half4 hi, lo;
                hi[0] = (_Float16)ra[p].x; lo[0] = (_Float16)(ra[p].x - (float)hi[0]);
                hi[1] = (_Float16)ra[p].y; lo[1] = (_Float16)(ra[p].y - (float)hi[1]);
                hi[2] = (_Float16)ra[p].z; lo[2] = (_Float16)(ra[p].z - (float)hi[2]);
                hi[3] = (_Float16)ra[p].w; lo[3] = (_Float16)(ra[p].w - (float)hi[3]);
                *(half4*)&u.t[0][oa] = hi;
                *(half4*)&u.t[1][oa] = lo;
                hi[0] = (_Float16)rb[p].x; lo[0] = (_Float16)(rb[p].x - (float)hi[0]);
                hi[1] = (_Float16)rb[p].y; lo[1] = (_Float16)(rb[p].y - (float)hi[1]);
                hi[2] = (_Float16)rb[p].z; lo[2] = (_Float16)(rb[p].z - (float)hi[2]);
                hi[3] = (_Float16)rb[p].w; lo[3] = (_Float16)(rb[p].w - (float)hi[3]);
                *(half4*)&u.t[2][oa] = hi;
                *(half4*)&u.t[3][oa] = lo;
            }
            __syncthreads();

            if (k0 + BK < D_) {
                #pragma unroll
                for (int p = 0; p < 4; ++p) {
                    const int r = sr + 32 * p;
                    ra[p] = *(const float4*)(memb + (size_t)r * D_ + k0 + BK + sc);
                    rb[p] = *(const float4*)(xb + (size_t)(s0 + r) * D_ + k0 + BK + sc);
                }
            }

            half8 ah[4], al[4];
            #pragma unroll
            for (int mt = 0; mt < 4; ++mt) {
                const int o = lds_off(wm + mt * 16 + fm, fkc * 8);
                ah[mt] = *(const half8*)&u.t[0][o];
                al[mt] = *(const half8*)&u.t[1][o];
            }
            #pragma unroll
            for (int st = 0; st < 4; ++st) {
                const int o = lds_off(wsj + st * 16 + fm, fkc * 8);
                const half8 bh = *(const half8*)&u.t[2][o];
                const half8 bl = *(const half8*)&u.t[3][o];
                #pragma unroll
                for (int mt = 0; mt < 4; ++mt)
                    acc[mt][st] = __builtin_amdgcn_mfma_f32_16x16x32_f16(ah[mt], bh, acc[mt][st], 0, 0, 0);
                #pragma unroll
                for (int mt = 0; mt < 4; ++mt)
                    acc[mt][st] = __builtin_amdgcn_mfma_f32_16x16x32_f16(ah[mt], bl, acc[mt][st], 0, 0, 0);
                #pragma unroll
                for (int mt = 0; mt < 4; ++mt)
                    acc[mt][st] = __builtin_amdgcn_mfma_f32_16x16x32_f16(al[mt], bh, acc[mt][st], 0, 0, 0);
            }
        }

        #pragma unroll
        for (int st = 0; st < 4; ++st) {
            const float sn = invnx[b * SX_ + s0 + wsj + st * 16 + fm];
            #pragma unroll
            for (int mt = 0; mt < 4; ++mt)
                #pragma unroll
                for (int j = 0; j < 4; ++j)
                    part[mt][j] = fmaxf(part[mt][j], acc[mt][st][j] * sn);
        }
    }

    #pragma unroll
    for (int off = 1; off < 16; off <<= 1)
        #pragma unroll
        for (int mt = 0; mt < 4; ++mt)
            #pragma unroll
            for (int j = 0; j < 4; ++j)
                part[mt][j] = fmaxf(part[mt][j], __shfl_xor(part[mt][j], off));

    __syncthreads();
    if (fm == 0) {
        #pragma unroll
        for (int mt = 0; mt < 4; ++mt)
            #pragma unroll
            for (int j = 0; j < 4; ++j)
                u.red[wid & 1][wm + mt * 16 + fkc * 4 + j] = part[mt][j];
    }
    __syncthreads();
    if (tid < BM) {
        const float v = fmaxf(u.red[0][tid], u.red[1][tid]);
        rowmax[(size_t)b * SM_ + m0 + tid] = v * invnm[b * SM_ + m0 + tid];
    }
}

// ---------------------------------------------------------------------------
// Kernel 3: per batch top-5 (tie -> lower index) + gather + index write.
// ---------------------------------------------------------------------------
__global__ __launch_bounds__(256) void top5_gather_kernel(
    const float* __restrict__ rowmax,
    const float* __restrict__ mem,
    float* __restrict__ out)
{
    __shared__ float vals[SM_];
    __shared__ float rv[256];
    __shared__ int   ri[256];
    __shared__ int   topidx[TOPK_];

    const int b = blockIdx.x, tid = threadIdx.x;
    const float* rm = rowmax + (size_t)b * SM_;
    for (int i = tid; i < SM_; i += 256) vals[i] = rm[i];
    __syncthreads();

    for (int k = 0; k < TOPK_; ++k) {
        float bestv = -INFINITY;
        int   besti = SM_;
        #pragma unroll
        for (int uu = 0; uu < SM_ / 256; ++uu) {
            const int idx = tid * (SM_ / 256) + uu;
            const float v = vals[idx];
            if (v > bestv) { bestv = v; besti = idx; }
        }
        rv[tid] = bestv; ri[tid] = besti;
        __syncthreads();
        for (int off = 128; off > 0; off >>= 1) {
            if (tid < off) {
                const float ov = rv[tid + off]; const int oi = ri[tid + off];
                if (ov > rv[tid] || (ov == rv[tid] && oi < ri[tid])) { rv[tid] = ov; ri[tid] = oi; }
            }
            __syncthreads();
        }
        if (tid == 0) { topidx[k] = ri[0]; vals[ri[0]] = -INFINITY; }
        __syncthreads();
    }

    const float* memb = mem + (size_t)b * SM_ * D_;
    #pragma unroll
    for (int k = 0; k < TOPK_; ++k)
        out[(size_t)k * B_ * D_ + (size_t)b * D_ + tid] = memb[(size_t)topidx[k] * D_ + tid];
    if (tid < TOPK_) out[(size_t)TOPK_ * B_ * D_ + b * TOPK_ + tid] = (float)topidx[tid];
}

// ---------------------------------------------------------------------------
extern "C" void kernel_launch(void* const* d_in, const int* in_sizes, int n_in,
                              void* d_out, int out_size, void* d_ws, size_t ws_size,
                              hipStream_t stream)
{
    const float* x   = (const float*)d_in[0];   // [32, 512, 256]
    const float* mem = (const float*)d_in[1];   // [32, 4096, 256]
    float* out = (float*)d_out;

    // big-ws layout (bytes): xh 8M | xl 8M | mh 64M | ml 64M | rowmax 512K
    const size_t XH_B = (size_t)B_ * SX_ * D_ * 2;   //  8,388,608
    const size_t MH_B = (size_t)B_ * SM_ * D_ * 2;   // 67,108,864
    const size_t NEED = 2 * XH_B + 2 * MH_B + (size_t)B_ * SM_ * 4;

    if (ws_size >= NEED) {
        char* w = (char*)d_ws;
        _Float16* xh = (_Float16*)(w);
        _Float16* xl = (_Float16*)(w + XH_B);
        _Float16* mh = (_Float16*)(w + 2 * XH_B);
        _Float16* ml = (_Float16*)(w + 2 * XH_B + MH_B);
        float* rowmax = (float*)(w + 2 * XH_B + 2 * MH_B);

        prep_kernel<<<(B_ * SX_) / 4, 256, 0, stream>>>(x, xh, xl, B_ * SX_);
        prep_kernel<<<(B_ * SM_) / 4, 256, 0, stream>>>(mem, mh, ml, B_ * SM_);

        dim3 grid(SM_ / BM, B_);
        gemm16_max_kernel<<<grid, 512, 0, stream>>>(xh, xl, mh, ml, rowmax);
        top5_gather_kernel<<<B_, 256, 0, stream>>>(rowmax, mem, out);
    } else {
        float* invnx  = (float*)d_ws;
        float* invnm  = invnx + B_ * SX_;
        float* rowmax = invnm + B_ * SM_;

        invnorm_kernel<<<(B_ * SX_) / 4, 256, 0, stream>>>(x, invnx, B_ * SX_);
        invnorm_kernel<<<(B_ * SM_) / 4, 256, 0, stream>>>(mem, invnm, B_ * SM_);
        dim3 grid(SM_ / BM, B_);
        gemm_max_kernel<<<grid, 256, 0, stream>>>(x, mem, invnx, invnm, rowmax);
        top5_gather_kernel<<<B_, 256, 0, stream>>>(rowmax, mem, out);
    }
}